// Round 16
// baseline (1422.675 us; speedup 1.0000x reference)
//
#include <hip/hip_runtime.h>
#include <hip/hip_fp16.h>
#include <hip/hip_cooperative_groups.h>

namespace cg = cooperative_groups;

// ---------------------------------------------------------------------------
// GCN (3 layers) + global mean pool + linear, fp32 in/out, MI355X.
// t'[i] = dinv[i] * h[i] W^T; h_next[i] = relu(dinv[i]*(t'[i]+sum t'[j]) + b)
// R3-R5: scattered 4B global stores/atomics = ~32B HBM sector each. Dense only.
// R9: fp16 t (128B row = 1 L2 line), absmax 1.2e-4.
// R11: LDS float-atomic scatter = never. R13: per-node barrier fusion = never.
// R14: 317us @ 10 launches; ~13us/launch = 41% of runtime.
// R15 (failed): cooperative launch with hard-coded grid=1024 never ran
//   (zero output) -- grid > runtime's max co-resident, unchecked error.
// R16: query occupancy + CU count per call, grid-stride by gridDim.x,
//   CHECK the launch result, fall back to the R14 10-launch path on failure.
//   LDS union shrunk to 16KB (stage[CAPB]).
// ---------------------------------------------------------------------------

#define CAPB 3072
#define BINTILE 4096
#define MAXGRID 1024

struct SMem {
    union {
        struct { int lcnt[512]; int gbase[512]; } bin;                     // 4KB
        struct { int hist[128]; int lofs[129]; int redbuf[256]; int stage[CAPB]; } sf; // 14.3KB
        struct { float hs[64 * 64]; } mm;                                  // 16KB
        struct { float red[4][64]; } pf;                                   // 1KB
    };
};

// ---------------- persistent-kernel phase bodies (grid-stride) -------------

__device__ __forceinline__ void mm_body(const float* __restrict__ h,
                                        const float* __restrict__ W,
                                        const float* __restrict__ dinv,
                                        __half* __restrict__ t,
                                        float* hs, int n) {
    int tid  = threadIdx.x;
    int lane = tid & 63;
    int wave = tid >> 6;
    float4 wreg[16];
    const float4* W4 = (const float4*)(W + lane * 64);
#pragma unroll
    for (int q = 0; q < 16; ++q) wreg[q] = W4[q];
    int ntiles = (n + 63) / 64;
    for (int tile = blockIdx.x; tile < ntiles; tile += gridDim.x) {
        int base  = tile * 64;
        int nrows = min(64, n - base);
        const float4* h4  = (const float4*)(h + (size_t)base * 64);
        float4*       hs4 = (float4*)hs;
        __syncthreads();
        for (int idx = tid; idx < nrows * 16; idx += 256) hs4[idx] = h4[idx];
        __syncthreads();
        for (int r = wave * 16; r < wave * 16 + 16; ++r) {
            int i = base + r;
            if (i >= n) break;
            const float4* row = (const float4*)(hs + r * 64);
            float acc = 0.0f;
#pragma unroll
            for (int q = 0; q < 16; ++q) {
                float4 hv = row[q];
                acc += hv.x * wreg[q].x + hv.y * wreg[q].y +
                       hv.z * wreg[q].z + hv.w * wreg[q].w;
            }
            t[(size_t)i * 64 + lane] = __float2half(acc * dinv[i]);
        }
    }
}

__device__ __forceinline__ void agg_body(const __half* __restrict__ t,
                                         const int* __restrict__ rp,
                                         const int* __restrict__ cs,
                                         const float* __restrict__ dinv,
                                         const float* __restrict__ bias,
                                         float* __restrict__ hout, int n) {
    int lane = threadIdx.x & 63;
    int grp  = lane >> 4;
    int fo   = (lane & 15) << 2;
    int gw0  = blockIdx.x * 4 + (threadIdx.x >> 6);
    for (int i = gw0; i < n; i += gridDim.x * 4) {
        int beg = rp[i];
        int end = rp[i + 1];
        float4 a0 = make_float4(0.f, 0.f, 0.f, 0.f);
        float4 a1 = a0, a2 = a0, a3 = a0;
        int e = beg + grp;
        for (; e + 12 < end; e += 16) {
            int s0 = cs[e];
            int s1 = cs[e + 4];
            int s2 = cs[e + 8];
            int s3 = cs[e + 12];
            uint2 u0 = *(const uint2*)(t + (size_t)s0 * 64 + fo);
            uint2 u1 = *(const uint2*)(t + (size_t)s1 * 64 + fo);
            uint2 u2 = *(const uint2*)(t + (size_t)s2 * 64 + fo);
            uint2 u3 = *(const uint2*)(t + (size_t)s3 * 64 + fo);
            float2 f;
            f = __half22float2(*(const __half2*)&u0.x); a0.x += f.x; a0.y += f.y;
            f = __half22float2(*(const __half2*)&u0.y); a0.z += f.x; a0.w += f.y;
            f = __half22float2(*(const __half2*)&u1.x); a1.x += f.x; a1.y += f.y;
            f = __half22float2(*(const __half2*)&u1.y); a1.z += f.x; a1.w += f.y;
            f = __half22float2(*(const __half2*)&u2.x); a2.x += f.x; a2.y += f.y;
            f = __half22float2(*(const __half2*)&u2.y); a2.z += f.x; a2.w += f.y;
            f = __half22float2(*(const __half2*)&u3.x); a3.x += f.x; a3.y += f.y;
            f = __half22float2(*(const __half2*)&u3.y); a3.z += f.x; a3.w += f.y;
        }
        for (; e < end; e += 4) {
            int s = cs[e];
            uint2 u = *(const uint2*)(t + (size_t)s * 64 + fo);
            float2 f;
            f = __half22float2(*(const __half2*)&u.x); a1.x += f.x; a1.y += f.y;
            f = __half22float2(*(const __half2*)&u.y); a1.z += f.x; a1.w += f.y;
        }
        float4 acc;
        acc.x = (a0.x + a1.x) + (a2.x + a3.x);
        acc.y = (a0.y + a1.y) + (a2.y + a3.y);
        acc.z = (a0.z + a1.z) + (a2.z + a3.z);
        acc.w = (a0.w + a1.w) + (a2.w + a3.w);
        acc.x += __shfl_xor(acc.x, 16, 64);
        acc.y += __shfl_xor(acc.y, 16, 64);
        acc.z += __shfl_xor(acc.z, 16, 64);
        acc.w += __shfl_xor(acc.w, 16, 64);
        acc.x += __shfl_xor(acc.x, 32, 64);
        acc.y += __shfl_xor(acc.y, 32, 64);
        acc.z += __shfl_xor(acc.z, 32, 64);
        acc.w += __shfl_xor(acc.w, 32, 64);
        if (grp == 0) {
            uint2 su = *(const uint2*)(t + (size_t)i * 64 + fo);
            float2 s01 = __half22float2(*(const __half2*)&su.x);
            float2 s23 = __half22float2(*(const __half2*)&su.y);
            float4 bv = *(const float4*)(bias + fo);
            float  dv = dinv[i];
            float4 o;
            o.x = fmaxf(fmaf(dv, acc.x + s01.x, bv.x), 0.0f);
            o.y = fmaxf(fmaf(dv, acc.y + s01.y, bv.y), 0.0f);
            o.z = fmaxf(fmaf(dv, acc.z + s23.x, bv.z), 0.0f);
            o.w = fmaxf(fmaf(dv, acc.w + s23.y, bv.w), 0.0f);
            *(float4*)(hout + (size_t)i * 64 + fo) = o;
        }
    }
}

__global__ __launch_bounds__(256, 4) void gnn_kernel(
    const float* __restrict__ x, const int* __restrict__ esrc,
    const int* __restrict__ edst, const int* __restrict__ batch,
    const float* __restrict__ W1, const float* __restrict__ b1,
    const float* __restrict__ W2, const float* __restrict__ b2,
    const float* __restrict__ W3, const float* __restrict__ b3,
    const float* __restrict__ Wl, const float* __restrict__ bl,
    float* __restrict__ out, float* __restrict__ dinv,
    int* __restrict__ rp, int* __restrict__ csr,
    __half* __restrict__ bufT, float* __restrict__ bufB,
    int* __restrict__ fctr, int2* __restrict__ recs2,
    int n, int e, int nb)
{
    cg::grid_group grid = cg::this_grid();
    __shared__ SMem sm;
    int tid = threadIdx.x;

    // P0: zero fctr
    for (int idx = blockIdx.x * 256 + tid; idx < 512; idx += gridDim.x * 256)
        fctr[idx] = 0;
    grid.sync();

    // P1: bin edges into 512 dst-ranges (fixed cap CAPB); dense 64B runs.
    int nTiles = (e + BINTILE - 1) / BINTILE;
    for (int tile = blockIdx.x; tile < nTiles; tile += gridDim.x) {
        int s0 = tile * BINTILE;
        sm.bin.lcnt[tid] = 0;
        sm.bin.lcnt[tid + 256] = 0;
        __syncthreads();
        int dv[16], bk[16];
#pragma unroll
        for (int k = 0; k < 16; ++k) {
            int i = s0 + tid + k * 256;
            if (i < e) {
                dv[k] = edst[i];
                bk[k] = (int)((512LL * dv[k]) / n);
                atomicAdd(&sm.bin.lcnt[bk[k]], 1);
            } else {
                bk[k] = -1;
            }
        }
        __syncthreads();
#pragma unroll
        for (int j = 0; j < 2; ++j) {
            int b = tid + j * 256;
            sm.bin.gbase[b] = b * CAPB + atomicAdd(&fctr[b], sm.bin.lcnt[b]);
            sm.bin.lcnt[b]  = 0;
        }
        __syncthreads();
#pragma unroll
        for (int k = 0; k < 16; ++k) {
            if (bk[k] >= 0) {
                int i = s0 + tid + k * 256;
                int p = sm.bin.gbase[bk[k]] + atomicAdd(&sm.bin.lcnt[bk[k]], 1);
                if (p < (bk[k] + 1) * CAPB) recs2[p] = make_int2(esrc[i], dv[k]);
            }
        }
        __syncthreads();
    }
    grid.sync();

    // P2: per-bucket counting sort -> dense csr; produces rp/dinv.
    for (int g = blockIdx.x; g < 512; g += gridDim.x) {
        int N0 = (int)(((long long)n * g + 511) / 512);
        int N1 = (int)(((long long)n * (g + 1) + 511) / 512);
        int nn = N1 - N0;  // <= 98
        int partial = 0;
        for (int j = tid; j < g; j += 256) partial += min(fctr[j], CAPB);
        sm.sf.redbuf[tid] = partial;
        if (tid < 128) sm.sf.hist[tid] = 0;
        __syncthreads();
        for (int s = 128; s > 0; s >>= 1) {
            if (tid < s) sm.sf.redbuf[tid] += sm.sf.redbuf[tid + s];
            __syncthreads();
        }
        int base = sm.sf.redbuf[0];
        const int2* my = recs2 + (size_t)g * CAPB;
        int total = min(fctr[g], CAPB);
        for (int i = tid; i < total; i += 256)
            atomicAdd(&sm.sf.hist[my[i].y - N0], 1);
        __syncthreads();
        if (tid == 0) {
            int acc = 0;
            for (int k = 0; k < nn; ++k) { sm.sf.lofs[k] = acc; acc += sm.sf.hist[k]; }
            sm.sf.lofs[nn] = acc;
        }
        __syncthreads();
        if (tid < 128) sm.sf.hist[tid] = 0;
        __syncthreads();
        for (int i = tid; i < total; i += 256) {
            int2 rec = my[i];
            int  li  = rec.y - N0;
            int  pos = sm.sf.lofs[li] + atomicAdd(&sm.sf.hist[li], 1);
            sm.sf.stage[pos] = rec.x;  // pos < total <= CAPB
        }
        __syncthreads();
        for (int j = tid; j < total; j += 256) csr[base + j] = sm.sf.stage[j];
        if (tid < nn) {
            rp[N0 + tid]   = base + sm.sf.lofs[tid];
            int deg        = sm.sf.lofs[tid + 1] - sm.sf.lofs[tid];
            dinv[N0 + tid] = rsqrtf((float)(deg + 1));
        }
        if (g == 511 && tid == 0) rp[n] = base + total;
        __syncthreads();
    }
    grid.sync();

    mm_body(x, W1, dinv, bufT, sm.mm.hs, n);
    grid.sync();
    agg_body(bufT, rp, csr, dinv, b1, bufB, n);
    grid.sync();
    mm_body(bufB, W2, dinv, bufT, sm.mm.hs, n);
    grid.sync();
    agg_body(bufT, rp, csr, dinv, b2, bufB, n);
    grid.sync();
    mm_body(bufB, W3, dinv, bufT, sm.mm.hs, n);
    grid.sync();
    agg_body(bufT, rp, csr, dinv, b3, bufB, n);
    grid.sync();

    // P_final: fused mean-pool + linear, block-per-graph, zero atomics.
    int lane = tid & 63;
    int w    = tid >> 6;
    for (int b = blockIdx.x; b < nb; b += gridDim.x) {
        int l = 0, r = n;
        while (l < r) { int m = (l + r) >> 1; if (batch[m] < b) l = m + 1; else r = m; }
        int lo = l;
        r = n;
        while (l < r) { int m = (l + r) >> 1; if (batch[m] < b + 1) l = m + 1; else r = m; }
        int hi = l;
        float acc = 0.0f;
        for (int i = lo + w; i < hi; i += 4) acc += bufB[(size_t)i * 64 + lane];
        __syncthreads();
        sm.pf.red[w][lane] = acc;
        __syncthreads();
        if (w == 0) {
            float s = (sm.pf.red[0][lane] + sm.pf.red[1][lane]) +
                      (sm.pf.red[2][lane] + sm.pf.red[3][lane]);
            float c = (float)(hi - lo);
            sm.pf.red[0][lane] = s / fmaxf(c, 1.0f);
        }
        __syncthreads();
        if (tid < 16) {
            float a = bl[tid];
            const float* wr = Wl + tid * 64;
#pragma unroll
            for (int k = 0; k < 64; ++k) a += sm.pf.red[0][k] * wr[k];
            out[b * 16 + tid] = a;
        }
        __syncthreads();
    }
}

// ---------------- R14 fallback kernels (proven, 10 launches) ---------------

__global__ __launch_bounds__(256) void init_kernel(int* __restrict__ fctr) {
    int idx = blockIdx.x * blockDim.x + threadIdx.x;
    if (idx < 512) fctr[idx] = 0;
}

__global__ __launch_bounds__(256) void bin512_kernel(const int* __restrict__ src,
                                                     const int* __restrict__ dst,
                                                     int* __restrict__ fctr,
                                                     int2* __restrict__ recs2,
                                                     int e, int n) {
    __shared__ int lcnt[512], gbase[512];
    int tid = threadIdx.x;
    int s0  = blockIdx.x * BINTILE;
    lcnt[tid] = 0;
    lcnt[tid + 256] = 0;
    __syncthreads();
    int dv[16], bk[16];
#pragma unroll
    for (int k = 0; k < 16; ++k) {
        int i = s0 + tid + k * 256;
        if (i < e) {
            dv[k] = dst[i];
            bk[k] = (int)((512LL * dv[k]) / n);
            atomicAdd(&lcnt[bk[k]], 1);
        } else {
            bk[k] = -1;
        }
    }
    __syncthreads();
#pragma unroll
    for (int j = 0; j < 2; ++j) {
        int b = tid + j * 256;
        gbase[b] = b * CAPB + atomicAdd(&fctr[b], lcnt[b]);
        lcnt[b]  = 0;
    }
    __syncthreads();
#pragma unroll
    for (int k = 0; k < 16; ++k) {
        if (bk[k] >= 0) {
            int i = s0 + tid + k * 256;
            int p = gbase[bk[k]] + atomicAdd(&lcnt[bk[k]], 1);
            if (p < (bk[k] + 1) * CAPB) recs2[p] = make_int2(src[i], dv[k]);
        }
    }
}

__global__ __launch_bounds__(256) void sortfill_kernel(const int2* __restrict__ recs2,
                                                       const int* __restrict__ fctr,
                                                       int* __restrict__ rp,
                                                       float* __restrict__ dinv,
                                                       int* __restrict__ csr, int n) {
    __shared__ int hist[128];
    __shared__ int lofs[129];
    __shared__ int stage[CAPB];
    __shared__ int redbuf[256];
    int g   = blockIdx.x;
    int N0  = (int)(((long long)n * g + 511) / 512);
    int N1  = (int)(((long long)n * (g + 1) + 511) / 512);
    int nn  = N1 - N0;
    int tid = threadIdx.x;
    int partial = 0;
    for (int j = tid; j < g; j += 256) partial += min(fctr[j], CAPB);
    redbuf[tid] = partial;
    if (tid < 128) hist[tid] = 0;
    __syncthreads();
    for (int s = 128; s > 0; s >>= 1) {
        if (tid < s) redbuf[tid] += redbuf[tid + s];
        __syncthreads();
    }
    int base = redbuf[0];
    const int2* my = recs2 + (size_t)g * CAPB;
    int total = min(fctr[g], CAPB);
    for (int i = tid; i < total; i += 256)
        atomicAdd(&hist[my[i].y - N0], 1);
    __syncthreads();
    if (tid == 0) {
        int acc = 0;
        for (int k = 0; k < nn; ++k) { lofs[k] = acc; acc += hist[k]; }
        lofs[nn] = acc;
    }
    __syncthreads();
    if (tid < 128) hist[tid] = 0;
    __syncthreads();
    for (int i = tid; i < total; i += 256) {
        int2 rec = my[i];
        int  li  = rec.y - N0;
        int  pos = lofs[li] + atomicAdd(&hist[li], 1);
        stage[pos] = rec.x;
    }
    __syncthreads();
    for (int j = tid; j < total; j += 256) csr[base + j] = stage[j];
    if (tid < nn) {
        rp[N0 + tid]   = base + lofs[tid];
        int deg        = lofs[tid + 1] - lofs[tid];
        dinv[N0 + tid] = rsqrtf((float)(deg + 1));
    }
    if (g == 511 && tid == 0) rp[n] = base + total;
}

__global__ __launch_bounds__(256) void mm_kernel(const float* __restrict__ h,
                                                 const float* __restrict__ W,
                                                 const float* __restrict__ dinv,
                                                 __half* __restrict__ t, int n) {
    __shared__ float hs[64 * 64];
    mm_body(h, W, dinv, t, hs, n);  // gridDim.x == ntiles when launched 1:1
}

__global__ __launch_bounds__(256) void agg_kernel(const __half* __restrict__ t,
                                                  const int* __restrict__ rp,
                                                  const int* __restrict__ cs,
                                                  const float* __restrict__ dinv,
                                                  const float* __restrict__ bias,
                                                  float* __restrict__ hout, int n) {
    agg_body(t, rp, cs, dinv, bias, hout, n);
}

__global__ __launch_bounds__(256) void poolfinal_kernel(const float* __restrict__ h,
                                                        const int* __restrict__ batch,
                                                        const float* __restrict__ Wl,
                                                        const float* __restrict__ bl,
                                                        float* __restrict__ out,
                                                        int n) {
    __shared__ float red[4][64];
    int b    = blockIdx.x;
    int tid  = threadIdx.x;
    int lane = tid & 63;
    int w    = tid >> 6;
    int l = 0, r = n;
    while (l < r) { int m = (l + r) >> 1; if (batch[m] < b) l = m + 1; else r = m; }
    int lo = l;
    r = n;
    while (l < r) { int m = (l + r) >> 1; if (batch[m] < b + 1) l = m + 1; else r = m; }
    int hi = l;
    float acc = 0.0f;
    for (int i = lo + w; i < hi; i += 4) acc += h[(size_t)i * 64 + lane];
    red[w][lane] = acc;
    __syncthreads();
    if (w == 0) {
        float s = (red[0][lane] + red[1][lane]) + (red[2][lane] + red[3][lane]);
        float c = (float)(hi - lo);
        red[0][lane] = s / fmaxf(c, 1.0f);
    }
    __syncthreads();
    if (tid < 16) {
        float a = bl[tid];
        const float* wr = Wl + tid * 64;
#pragma unroll
        for (int k = 0; k < 64; ++k) a += red[0][k] * wr[k];
        out[b * 16 + tid] = a;
    }
}

extern "C" void kernel_launch(void* const* d_in, const int* in_sizes, int n_in,
                              void* d_out, int out_size, void* d_ws, size_t ws_size,
                              hipStream_t stream) {
    const float* x    = (const float*)d_in[0];
    const int*   ei   = (const int*)d_in[1];
    const int*   batch= (const int*)d_in[2];
    const float* W1   = (const float*)d_in[3];
    const float* b1   = (const float*)d_in[4];
    const float* W2   = (const float*)d_in[5];
    const float* b2   = (const float*)d_in[6];
    const float* W3   = (const float*)d_in[7];
    const float* b3   = (const float*)d_in[8];
    const float* Wl   = (const float*)d_in[9];
    const float* bl   = (const float*)d_in[10];
    float* out = (float*)d_out;

    int n  = in_sizes[0] / 64;   // 50000 nodes
    int e  = in_sizes[1] / 2;    // 1250000 edges
    int nb = out_size / 16;      // 512 graphs

    const int* esrc = ei;
    const int* edst = ei + e;

    char* p = (char*)d_ws;
    auto carve = [&](size_t bytes) {
        char* r = p;
        p += (bytes + 255) & ~(size_t)255;
        return r;
    };
    size_t featBytes = (size_t)n * 64 * 4;
    size_t recsBytes = (size_t)512 * CAPB * 8;
    size_t bufBBytes = recsBytes > featBytes ? recsBytes : featBytes;

    float*  dinv = (float*)carve((size_t)n * 4);
    int*    rp   = (int*)  carve((size_t)(n + 1) * 4);
    int*    csr  = (int*)  carve((size_t)e * 4);
    __half* bufT = (__half*)carve((size_t)n * 64 * 2);
    float*  bufB = (float*)carve(bufBBytes);
    int*    fctr = (int*)  carve(512 * 4);
    int2*   recs2 = (int2*)bufB;

    dim3 blk(256);
    int gBIN = (e + BINTILE - 1) / BINTILE;
    int gMM  = (n + 63) / 64;
    int gAGG = (n + 3) / 4;

    // --- try the single cooperative launch, with queried limits ---
    bool done = false;
    int coop = 0, dev = 0;
    hipGetDevice(&dev);
    hipDeviceGetAttribute(&coop, hipDeviceAttributeCooperativeLaunch, dev);
    if (coop) {
        int blocksPerCU = 0, numCU = 0;
        hipError_t qe = hipOccupancyMaxActiveBlocksPerMultiprocessor(
            &blocksPerCU, (const void*)gnn_kernel, 256, 0);
        hipDeviceGetAttribute(&numCU, hipDeviceAttributeMultiprocessorCount, dev);
        if (qe == hipSuccess && blocksPerCU > 0 && numCU > 0) {
            int grid = blocksPerCU * numCU;
            if (grid > MAXGRID) grid = MAXGRID;
            void* args[] = { &x, &esrc, &edst, &batch, &W1, &b1, &W2, &b2,
                             &W3, &b3, &Wl, &bl, &out, &dinv, &rp, &csr,
                             &bufT, &bufB, &fctr, &recs2, &n, &e, &nb };
            hipError_t le = hipLaunchCooperativeKernel(
                (const void*)gnn_kernel, dim3(grid), dim3(256), args, 0, stream);
            if (le == hipSuccess) {
                done = true;
            } else {
                (void)hipGetLastError();  // clear error state
            }
        } else {
            (void)hipGetLastError();
        }
    }

    if (!done) {
        // --- proven R14 path: 10 launches ---
        init_kernel<<<2, blk, 0, stream>>>(fctr);
        bin512_kernel<<<gBIN, blk, 0, stream>>>(esrc, edst, fctr, recs2, e, n);
        sortfill_kernel<<<512, blk, 0, stream>>>(recs2, fctr, rp, dinv, csr, n);
        mm_kernel<<<gMM, blk, 0, stream>>>(x, W1, dinv, bufT, n);
        agg_kernel<<<gAGG, blk, 0, stream>>>(bufT, rp, csr, dinv, b1, bufB, n);
        mm_kernel<<<gMM, blk, 0, stream>>>(bufB, W2, dinv, bufT, n);
        agg_kernel<<<gAGG, blk, 0, stream>>>(bufT, rp, csr, dinv, b2, bufB, n);
        mm_kernel<<<gMM, blk, 0, stream>>>(bufB, W3, dinv, bufT, n);
        agg_kernel<<<gAGG, blk, 0, stream>>>(bufT, rp, csr, dinv, b3, bufB, n);
        poolfinal_kernel<<<nb, blk, 0, stream>>>(bufB, batch, Wl, bl, out, n);
    }
}

// Round 17
// 316.300 us; speedup vs baseline: 4.4979x; 4.4979x over previous
//
#include <hip/hip_runtime.h>
#include <hip/hip_fp16.h>
#include <hip/hip_cooperative_groups.h>

namespace cg = cooperative_groups;

// ---------------------------------------------------------------------------
// GCN (3 layers) + global mean pool + linear, fp32 in/out, MI355X.
// t'[i] = dinv[i] * h[i] W^T; h_next[i] = relu(dinv[i]*(t'[i]+sum t'[j]) + b)
// R3-R5: scattered 4B global stores/atomics = ~32B HBM sector each. Dense only.
// R9: fp16 t (128B row = 1 L2 line), absmax 1.2e-4.
// R11: LDS float-atomic scatter = never. R13: per-node barrier fusion = never.
// R14: 317us @ 10 launches; ~13us/launch = 41% of runtime.
// R16 (counter-verified): __launch_bounds__(256,4) clamped the persistent
//   kernel to 64 VGPRs; mm's wreg[16] (64 VGPRs) spilled -> ~900MB scratch
//   traffic (FETCH 969MB, WRITE 394MB), 1650us. In a multi-phase persistent
//   kernel, regalloc is max-over-phases: never pin min-occupancy.
// R17: same persistent kernel, UNclamped (__launch_bounds__(256) only);
//   grid from occupancy query (cap 2048, floor 256); R14 fallback retained.
// ---------------------------------------------------------------------------

#define CAPB 3072
#define BINTILE 4096
#define MAXGRID 2048

struct SMem {
    union {
        struct { int lcnt[512]; int gbase[512]; } bin;                     // 4KB
        struct { int hist[128]; int lofs[129]; int redbuf[256]; int stage[CAPB]; } sf; // 14.3KB
        struct { float hs[64 * 64]; } mm;                                  // 16KB
        struct { float red[4][64]; } pf;                                   // 1KB
    };
};

// ---------------- phase bodies (grid-stride) -------------------------------

__device__ __forceinline__ void mm_body(const float* __restrict__ h,
                                        const float* __restrict__ W,
                                        const float* __restrict__ dinv,
                                        __half* __restrict__ t,
                                        float* hs, int n) {
    int tid  = threadIdx.x;
    int lane = tid & 63;
    int wave = tid >> 6;
    float4 wreg[16];
    const float4* W4 = (const float4*)(W + lane * 64);
#pragma unroll
    for (int q = 0; q < 16; ++q) wreg[q] = W4[q];
    int ntiles = (n + 63) / 64;
    for (int tile = blockIdx.x; tile < ntiles; tile += gridDim.x) {
        int base  = tile * 64;
        int nrows = min(64, n - base);
        const float4* h4  = (const float4*)(h + (size_t)base * 64);
        float4*       hs4 = (float4*)hs;
        __syncthreads();
        for (int idx = tid; idx < nrows * 16; idx += 256) hs4[idx] = h4[idx];
        __syncthreads();
        for (int r = wave * 16; r < wave * 16 + 16; ++r) {
            int i = base + r;
            if (i >= n) break;
            const float4* row = (const float4*)(hs + r * 64);
            float acc = 0.0f;
#pragma unroll
            for (int q = 0; q < 16; ++q) {
                float4 hv = row[q];
                acc += hv.x * wreg[q].x + hv.y * wreg[q].y +
                       hv.z * wreg[q].z + hv.w * wreg[q].w;
            }
            t[(size_t)i * 64 + lane] = __float2half(acc * dinv[i]);
        }
    }
}

__device__ __forceinline__ void agg_body(const __half* __restrict__ t,
                                         const int* __restrict__ rp,
                                         const int* __restrict__ cs,
                                         const float* __restrict__ dinv,
                                         const float* __restrict__ bias,
                                         float* __restrict__ hout, int n) {
    int lane = threadIdx.x & 63;
    int grp  = lane >> 4;
    int fo   = (lane & 15) << 2;
    int gw0  = blockIdx.x * 4 + (threadIdx.x >> 6);
    for (int i = gw0; i < n; i += gridDim.x * 4) {
        int beg = rp[i];
        int end = rp[i + 1];
        float4 a0 = make_float4(0.f, 0.f, 0.f, 0.f);
        float4 a1 = a0, a2 = a0, a3 = a0;
        int e = beg + grp;
        for (; e + 12 < end; e += 16) {
            int s0 = cs[e];
            int s1 = cs[e + 4];
            int s2 = cs[e + 8];
            int s3 = cs[e + 12];
            uint2 u0 = *(const uint2*)(t + (size_t)s0 * 64 + fo);
            uint2 u1 = *(const uint2*)(t + (size_t)s1 * 64 + fo);
            uint2 u2 = *(const uint2*)(t + (size_t)s2 * 64 + fo);
            uint2 u3 = *(const uint2*)(t + (size_t)s3 * 64 + fo);
            float2 f;
            f = __half22float2(*(const __half2*)&u0.x); a0.x += f.x; a0.y += f.y;
            f = __half22float2(*(const __half2*)&u0.y); a0.z += f.x; a0.w += f.y;
            f = __half22float2(*(const __half2*)&u1.x); a1.x += f.x; a1.y += f.y;
            f = __half22float2(*(const __half2*)&u1.y); a1.z += f.x; a1.w += f.y;
            f = __half22float2(*(const __half2*)&u2.x); a2.x += f.x; a2.y += f.y;
            f = __half22float2(*(const __half2*)&u2.y); a2.z += f.x; a2.w += f.y;
            f = __half22float2(*(const __half2*)&u3.x); a3.x += f.x; a3.y += f.y;
            f = __half22float2(*(const __half2*)&u3.y); a3.z += f.x; a3.w += f.y;
        }
        for (; e < end; e += 4) {
            int s = cs[e];
            uint2 u = *(const uint2*)(t + (size_t)s * 64 + fo);
            float2 f;
            f = __half22float2(*(const __half2*)&u.x); a1.x += f.x; a1.y += f.y;
            f = __half22float2(*(const __half2*)&u.y); a1.z += f.x; a1.w += f.y;
        }
        float4 acc;
        acc.x = (a0.x + a1.x) + (a2.x + a3.x);
        acc.y = (a0.y + a1.y) + (a2.y + a3.y);
        acc.z = (a0.z + a1.z) + (a2.z + a3.z);
        acc.w = (a0.w + a1.w) + (a2.w + a3.w);
        acc.x += __shfl_xor(acc.x, 16, 64);
        acc.y += __shfl_xor(acc.y, 16, 64);
        acc.z += __shfl_xor(acc.z, 16, 64);
        acc.w += __shfl_xor(acc.w, 16, 64);
        acc.x += __shfl_xor(acc.x, 32, 64);
        acc.y += __shfl_xor(acc.y, 32, 64);
        acc.z += __shfl_xor(acc.z, 32, 64);
        acc.w += __shfl_xor(acc.w, 32, 64);
        if (grp == 0) {
            uint2 su = *(const uint2*)(t + (size_t)i * 64 + fo);
            float2 s01 = __half22float2(*(const __half2*)&su.x);
            float2 s23 = __half22float2(*(const __half2*)&su.y);
            float4 bv = *(const float4*)(bias + fo);
            float  dv = dinv[i];
            float4 o;
            o.x = fmaxf(fmaf(dv, acc.x + s01.x, bv.x), 0.0f);
            o.y = fmaxf(fmaf(dv, acc.y + s01.y, bv.y), 0.0f);
            o.z = fmaxf(fmaf(dv, acc.z + s23.x, bv.z), 0.0f);
            o.w = fmaxf(fmaf(dv, acc.w + s23.y, bv.w), 0.0f);
            *(float4*)(hout + (size_t)i * 64 + fo) = o;
        }
    }
}

__global__ __launch_bounds__(256) void gnn_kernel(
    const float* __restrict__ x, const int* __restrict__ esrc,
    const int* __restrict__ edst, const int* __restrict__ batch,
    const float* __restrict__ W1, const float* __restrict__ b1,
    const float* __restrict__ W2, const float* __restrict__ b2,
    const float* __restrict__ W3, const float* __restrict__ b3,
    const float* __restrict__ Wl, const float* __restrict__ bl,
    float* __restrict__ out, float* __restrict__ dinv,
    int* __restrict__ rp, int* __restrict__ csr,
    __half* __restrict__ bufT, float* __restrict__ bufB,
    int* __restrict__ fctr, int2* __restrict__ recs2,
    int n, int e, int nb)
{
    cg::grid_group grid = cg::this_grid();
    __shared__ SMem sm;
    int tid = threadIdx.x;

    // P0: zero fctr
    for (int idx = blockIdx.x * 256 + tid; idx < 512; idx += gridDim.x * 256)
        fctr[idx] = 0;
    grid.sync();

    // P1: bin edges into 512 dst-ranges (fixed cap CAPB); dense 64B runs.
    int nTiles = (e + BINTILE - 1) / BINTILE;
    for (int tile = blockIdx.x; tile < nTiles; tile += gridDim.x) {
        int s0 = tile * BINTILE;
        sm.bin.lcnt[tid] = 0;
        sm.bin.lcnt[tid + 256] = 0;
        __syncthreads();
        int dv[16], bk[16];
#pragma unroll
        for (int k = 0; k < 16; ++k) {
            int i = s0 + tid + k * 256;
            if (i < e) {
                dv[k] = edst[i];
                bk[k] = (int)((512LL * dv[k]) / n);
                atomicAdd(&sm.bin.lcnt[bk[k]], 1);
            } else {
                bk[k] = -1;
            }
        }
        __syncthreads();
#pragma unroll
        for (int j = 0; j < 2; ++j) {
            int b = tid + j * 256;
            sm.bin.gbase[b] = b * CAPB + atomicAdd(&fctr[b], sm.bin.lcnt[b]);
            sm.bin.lcnt[b]  = 0;
        }
        __syncthreads();
#pragma unroll
        for (int k = 0; k < 16; ++k) {
            if (bk[k] >= 0) {
                int i = s0 + tid + k * 256;
                int p = sm.bin.gbase[bk[k]] + atomicAdd(&sm.bin.lcnt[bk[k]], 1);
                if (p < (bk[k] + 1) * CAPB) recs2[p] = make_int2(esrc[i], dv[k]);
            }
        }
        __syncthreads();
    }
    grid.sync();

    // P2: per-bucket counting sort -> dense csr; produces rp/dinv.
    for (int g = blockIdx.x; g < 512; g += gridDim.x) {
        int N0 = (int)(((long long)n * g + 511) / 512);
        int N1 = (int)(((long long)n * (g + 1) + 511) / 512);
        int nn = N1 - N0;  // <= 98
        int partial = 0;
        for (int j = tid; j < g; j += 256) partial += min(fctr[j], CAPB);
        sm.sf.redbuf[tid] = partial;
        if (tid < 128) sm.sf.hist[tid] = 0;
        __syncthreads();
        for (int s = 128; s > 0; s >>= 1) {
            if (tid < s) sm.sf.redbuf[tid] += sm.sf.redbuf[tid + s];
            __syncthreads();
        }
        int base = sm.sf.redbuf[0];
        const int2* my = recs2 + (size_t)g * CAPB;
        int total = min(fctr[g], CAPB);
        for (int i = tid; i < total; i += 256)
            atomicAdd(&sm.sf.hist[my[i].y - N0], 1);
        __syncthreads();
        if (tid == 0) {
            int acc = 0;
            for (int k = 0; k < nn; ++k) { sm.sf.lofs[k] = acc; acc += sm.sf.hist[k]; }
            sm.sf.lofs[nn] = acc;
        }
        __syncthreads();
        if (tid < 128) sm.sf.hist[tid] = 0;
        __syncthreads();
        for (int i = tid; i < total; i += 256) {
            int2 rec = my[i];
            int  li  = rec.y - N0;
            int  pos = sm.sf.lofs[li] + atomicAdd(&sm.sf.hist[li], 1);
            sm.sf.stage[pos] = rec.x;  // pos < total <= CAPB
        }
        __syncthreads();
        for (int j = tid; j < total; j += 256) csr[base + j] = sm.sf.stage[j];
        if (tid < nn) {
            rp[N0 + tid]   = base + sm.sf.lofs[tid];
            int deg        = sm.sf.lofs[tid + 1] - sm.sf.lofs[tid];
            dinv[N0 + tid] = rsqrtf((float)(deg + 1));
        }
        if (g == 511 && tid == 0) rp[n] = base + total;
        __syncthreads();
    }
    grid.sync();

    mm_body(x, W1, dinv, bufT, sm.mm.hs, n);
    grid.sync();
    agg_body(bufT, rp, csr, dinv, b1, bufB, n);
    grid.sync();
    mm_body(bufB, W2, dinv, bufT, sm.mm.hs, n);
    grid.sync();
    agg_body(bufT, rp, csr, dinv, b2, bufB, n);
    grid.sync();
    mm_body(bufB, W3, dinv, bufT, sm.mm.hs, n);
    grid.sync();
    agg_body(bufT, rp, csr, dinv, b3, bufB, n);
    grid.sync();

    // P_final: fused mean-pool + linear, block-per-graph, zero atomics.
    int lane = tid & 63;
    int w    = tid >> 6;
    for (int b = blockIdx.x; b < nb; b += gridDim.x) {
        int l = 0, r = n;
        while (l < r) { int m = (l + r) >> 1; if (batch[m] < b) l = m + 1; else r = m; }
        int lo = l;
        r = n;
        while (l < r) { int m = (l + r) >> 1; if (batch[m] < b + 1) l = m + 1; else r = m; }
        int hi = l;
        float acc = 0.0f;
        for (int i = lo + w; i < hi; i += 4) acc += bufB[(size_t)i * 64 + lane];
        __syncthreads();
        sm.pf.red[w][lane] = acc;
        __syncthreads();
        if (w == 0) {
            float s = (sm.pf.red[0][lane] + sm.pf.red[1][lane]) +
                      (sm.pf.red[2][lane] + sm.pf.red[3][lane]);
            float c = (float)(hi - lo);
            sm.pf.red[0][lane] = s / fmaxf(c, 1.0f);
        }
        __syncthreads();
        if (tid < 16) {
            float a = bl[tid];
            const float* wr = Wl + tid * 64;
#pragma unroll
            for (int k = 0; k < 64; ++k) a += sm.pf.red[0][k] * wr[k];
            out[b * 16 + tid] = a;
        }
        __syncthreads();
    }
}

// ---------------- R14 fallback kernels (proven, 10 launches) ---------------

__global__ __launch_bounds__(256) void init_kernel(int* __restrict__ fctr) {
    int idx = blockIdx.x * blockDim.x + threadIdx.x;
    if (idx < 512) fctr[idx] = 0;
}

__global__ __launch_bounds__(256) void bin512_kernel(const int* __restrict__ src,
                                                     const int* __restrict__ dst,
                                                     int* __restrict__ fctr,
                                                     int2* __restrict__ recs2,
                                                     int e, int n) {
    __shared__ int lcnt[512], gbase[512];
    int tid = threadIdx.x;
    int s0  = blockIdx.x * BINTILE;
    lcnt[tid] = 0;
    lcnt[tid + 256] = 0;
    __syncthreads();
    int dv[16], bk[16];
#pragma unroll
    for (int k = 0; k < 16; ++k) {
        int i = s0 + tid + k * 256;
        if (i < e) {
            dv[k] = dst[i];
            bk[k] = (int)((512LL * dv[k]) / n);
            atomicAdd(&lcnt[bk[k]], 1);
        } else {
            bk[k] = -1;
        }
    }
    __syncthreads();
#pragma unroll
    for (int j = 0; j < 2; ++j) {
        int b = tid + j * 256;
        gbase[b] = b * CAPB + atomicAdd(&fctr[b], lcnt[b]);
        lcnt[b]  = 0;
    }
    __syncthreads();
#pragma unroll
    for (int k = 0; k < 16; ++k) {
        if (bk[k] >= 0) {
            int i = s0 + tid + k * 256;
            int p = gbase[bk[k]] + atomicAdd(&lcnt[bk[k]], 1);
            if (p < (bk[k] + 1) * CAPB) recs2[p] = make_int2(src[i], dv[k]);
        }
    }
}

__global__ __launch_bounds__(256) void sortfill_kernel(const int2* __restrict__ recs2,
                                                       const int* __restrict__ fctr,
                                                       int* __restrict__ rp,
                                                       float* __restrict__ dinv,
                                                       int* __restrict__ csr, int n) {
    __shared__ int hist[128];
    __shared__ int lofs[129];
    __shared__ int stage[CAPB];
    __shared__ int redbuf[256];
    int g   = blockIdx.x;
    int N0  = (int)(((long long)n * g + 511) / 512);
    int N1  = (int)(((long long)n * (g + 1) + 511) / 512);
    int nn  = N1 - N0;
    int tid = threadIdx.x;
    int partial = 0;
    for (int j = tid; j < g; j += 256) partial += min(fctr[j], CAPB);
    redbuf[tid] = partial;
    if (tid < 128) hist[tid] = 0;
    __syncthreads();
    for (int s = 128; s > 0; s >>= 1) {
        if (tid < s) redbuf[tid] += redbuf[tid + s];
        __syncthreads();
    }
    int base = redbuf[0];
    const int2* my = recs2 + (size_t)g * CAPB;
    int total = min(fctr[g], CAPB);
    for (int i = tid; i < total; i += 256)
        atomicAdd(&hist[my[i].y - N0], 1);
    __syncthreads();
    if (tid == 0) {
        int acc = 0;
        for (int k = 0; k < nn; ++k) { lofs[k] = acc; acc += hist[k]; }
        lofs[nn] = acc;
    }
    __syncthreads();
    if (tid < 128) hist[tid] = 0;
    __syncthreads();
    for (int i = tid; i < total; i += 256) {
        int2 rec = my[i];
        int  li  = rec.y - N0;
        int  pos = lofs[li] + atomicAdd(&hist[li], 1);
        stage[pos] = rec.x;
    }
    __syncthreads();
    for (int j = tid; j < total; j += 256) csr[base + j] = stage[j];
    if (tid < nn) {
        rp[N0 + tid]   = base + lofs[tid];
        int deg        = lofs[tid + 1] - lofs[tid];
        dinv[N0 + tid] = rsqrtf((float)(deg + 1));
    }
    if (g == 511 && tid == 0) rp[n] = base + total;
}

__global__ __launch_bounds__(256) void mm_kernel(const float* __restrict__ h,
                                                 const float* __restrict__ W,
                                                 const float* __restrict__ dinv,
                                                 __half* __restrict__ t, int n) {
    __shared__ float hs[64 * 64];
    mm_body(h, W, dinv, t, hs, n);
}

__global__ __launch_bounds__(256) void agg_kernel(const __half* __restrict__ t,
                                                  const int* __restrict__ rp,
                                                  const int* __restrict__ cs,
                                                  const float* __restrict__ dinv,
                                                  const float* __restrict__ bias,
                                                  float* __restrict__ hout, int n) {
    agg_body(t, rp, cs, dinv, bias, hout, n);
}

__global__ __launch_bounds__(256) void poolfinal_kernel(const float* __restrict__ h,
                                                        const int* __restrict__ batch,
                                                        const float* __restrict__ Wl,
                                                        const float* __restrict__ bl,
                                                        float* __restrict__ out,
                                                        int n) {
    __shared__ float red[4][64];
    int b    = blockIdx.x;
    int tid  = threadIdx.x;
    int lane = tid & 63;
    int w    = tid >> 6;
    int l = 0, r = n;
    while (l < r) { int m = (l + r) >> 1; if (batch[m] < b) l = m + 1; else r = m; }
    int lo = l;
    r = n;
    while (l < r) { int m = (l + r) >> 1; if (batch[m] < b + 1) l = m + 1; else r = m; }
    int hi = l;
    float acc = 0.0f;
    for (int i = lo + w; i < hi; i += 4) acc += h[(size_t)i * 64 + lane];
    red[w][lane] = acc;
    __syncthreads();
    if (w == 0) {
        float s = (red[0][lane] + red[1][lane]) + (red[2][lane] + red[3][lane]);
        float c = (float)(hi - lo);
        red[0][lane] = s / fmaxf(c, 1.0f);
    }
    __syncthreads();
    if (tid < 16) {
        float a = bl[tid];
        const float* wr = Wl + tid * 64;
#pragma unroll
        for (int k = 0; k < 64; ++k) a += red[0][k] * wr[k];
        out[b * 16 + tid] = a;
    }
}

extern "C" void kernel_launch(void* const* d_in, const int* in_sizes, int n_in,
                              void* d_out, int out_size, void* d_ws, size_t ws_size,
                              hipStream_t stream) {
    const float* x    = (const float*)d_in[0];
    const int*   ei   = (const int*)d_in[1];
    const int*   batch= (const int*)d_in[2];
    const float* W1   = (const float*)d_in[3];
    const float* b1   = (const float*)d_in[4];
    const float* W2   = (const float*)d_in[5];
    const float* b2   = (const float*)d_in[6];
    const float* W3   = (const float*)d_in[7];
    const float* b3   = (const float*)d_in[8];
    const float* Wl   = (const float*)d_in[9];
    const float* bl   = (const float*)d_in[10];
    float* out = (float*)d_out;

    int n  = in_sizes[0] / 64;   // 50000 nodes
    int e  = in_sizes[1] / 2;    // 1250000 edges
    int nb = out_size / 16;      // 512 graphs

    const int* esrc = ei;
    const int* edst = ei + e;

    char* p = (char*)d_ws;
    auto carve = [&](size_t bytes) {
        char* r = p;
        p += (bytes + 255) & ~(size_t)255;
        return r;
    };
    size_t featBytes = (size_t)n * 64 * 4;
    size_t recsBytes = (size_t)512 * CAPB * 8;
    size_t bufBBytes = recsBytes > featBytes ? recsBytes : featBytes;

    float*  dinv = (float*)carve((size_t)n * 4);
    int*    rp   = (int*)  carve((size_t)(n + 1) * 4);
    int*    csr  = (int*)  carve((size_t)e * 4);
    __half* bufT = (__half*)carve((size_t)n * 64 * 2);
    float*  bufB = (float*)carve(bufBBytes);
    int*    fctr = (int*)  carve(512 * 4);
    int2*   recs2 = (int2*)bufB;

    dim3 blk(256);
    int gBIN = (e + BINTILE - 1) / BINTILE;
    int gMM  = (n + 63) / 64;
    int gAGG = (n + 3) / 4;

    // --- try the single cooperative launch, with queried limits ---
    bool done = false;
    int coop = 0, dev = 0;
    hipGetDevice(&dev);
    hipDeviceGetAttribute(&coop, hipDeviceAttributeCooperativeLaunch, dev);
    if (coop) {
        int blocksPerCU = 0, numCU = 0;
        hipError_t qe = hipOccupancyMaxActiveBlocksPerMultiprocessor(
            &blocksPerCU, (const void*)gnn_kernel, 256, 0);
        hipDeviceGetAttribute(&numCU, hipDeviceAttributeMultiprocessorCount, dev);
        if (qe == hipSuccess && blocksPerCU > 0 && numCU > 0) {
            int grid = blocksPerCU * numCU;
            if (grid > MAXGRID) grid = MAXGRID;
            if (grid >= 256) {  // need at least 1 block/CU to be worthwhile
                void* args[] = { &x, &esrc, &edst, &batch, &W1, &b1, &W2, &b2,
                                 &W3, &b3, &Wl, &bl, &out, &dinv, &rp, &csr,
                                 &bufT, &bufB, &fctr, &recs2, &n, &e, &nb };
                hipError_t le = hipLaunchCooperativeKernel(
                    (const void*)gnn_kernel, dim3(grid), dim3(256), args, 0,
                    stream);
                if (le == hipSuccess) {
                    done = true;
                } else {
                    (void)hipGetLastError();  // clear error state
                }
            }
        } else {
            (void)hipGetLastError();
        }
    }

    if (!done) {
        // --- proven R14 path: 10 launches ---
        init_kernel<<<2, blk, 0, stream>>>(fctr);
        bin512_kernel<<<gBIN, blk, 0, stream>>>(esrc, edst, fctr, recs2, e, n);
        sortfill_kernel<<<512, blk, 0, stream>>>(recs2, fctr, rp, dinv, csr, n);
        mm_kernel<<<gMM, blk, 0, stream>>>(x, W1, dinv, bufT, n);
        agg_kernel<<<gAGG, blk, 0, stream>>>(bufT, rp, csr, dinv, b1, bufB, n);
        mm_kernel<<<gMM, blk, 0, stream>>>(bufB, W2, dinv, bufT, n);
        agg_kernel<<<gAGG, blk, 0, stream>>>(bufT, rp, csr, dinv, b2, bufB, n);
        mm_kernel<<<gMM, blk, 0, stream>>>(bufB, W3, dinv, bufT, n);
        agg_kernel<<<gAGG, blk, 0, stream>>>(bufT, rp, csr, dinv, b3, bufB, n);
        poolfinal_kernel<<<nb, blk, 0, stream>>>(bufB, batch, Wl, bl, out, n);
    }
}